// Round 1
// baseline (704.181 us; speedup 1.0000x reference)
//
#include <hip/hip_runtime.h>
#include <math.h>

#define N_AGENT 60000
#define N_MAP   40000
#define N_NODES 100000
#define NE      3200000
#define HID     32
#define PERIODS 30

// ---------------- kernel 0: fold weights, softmax sum ----------------
__global__ void k_precompute(const float* Wz_c, const float* bz_c,
                             const float* Wh_c, const float* bh_c,
                             const float* Wz_l, const float* bz_l,
                             const float* Wh_l, const float* bh_l,
                             const float* attn,
                             float* Mz, float* Mh, float* bz_eff, float* bh_eff,
                             float* s_out) {
    int t = threadIdx.x;            // blockDim = 1024
    int k = t >> 5, c = t & 31;
    float mz = 0.f, mh = 0.f;
    for (int j = 0; j < HID; ++j) {
        mz += Wz_c[k * HID + j] * Wz_l[j * HID + c];   // Wz_l rows 0..31 (zeros half dead)
        mh += Wh_c[k * HID + j] * Wh_l[j * HID + c];
    }
    Mz[t] = mz; Mh[t] = mh;
    if (t < HID) {
        float bz = bz_l[t], bh = bh_l[t];
        for (int j = 0; j < HID; ++j) {
            bz += bz_c[j] * Wz_l[j * HID + t];
            bh += bh_c[j] * Wh_l[j * HID + t];
        }
        bz_eff[t] = bz; bh_eff[t] = bh;
    }
    if (t == 0) {
        float m = -1e30f;
        for (int i = 0; i < PERIODS; ++i) m = fmaxf(m, attn[i]);
        float S = 0.f;
        for (int i = 0; i < PERIODS; ++i) S += expf(attn[i] - m);
        float s = 0.f;
        for (int i = 0; i < PERIODS; ++i) s += expf(attn[i] - m) / S;
        *s_out = s;
    }
}

// ---------------- kernel 1: node encoders ----------------
__global__ void k_encode(const float* __restrict__ agent_x, const float* __restrict__ map_x,
                         const float* __restrict__ W_agent, const float* __restrict__ b_agent,
                         const float* __restrict__ W_map, const float* __restrict__ b_map,
                         float* __restrict__ x) {
    int t = blockIdx.x * blockDim.x + threadIdx.x;
    if (t >= N_NODES * HID) return;
    int i = t >> 5, c = t & 31;
    float acc;
    if (i < N_AGENT) {
        const float* row = agent_x + (size_t)i * 9;
        acc = b_agent[c];
#pragma unroll
        for (int k = 0; k < 9; ++k) acc += row[k] * W_agent[k * HID + c];
    } else {
        const float* row = map_x + (size_t)(i - N_AGENT) * 6;
        acc = b_map[c];
#pragma unroll
        for (int k = 0; k < 6; ++k) acc += row[k] * W_map[k * HID + c];
    }
    x[t] = acc;
}

// ---------------- kernel 2: in-degree count (all dsts) ----------------
__global__ void k_degree(const int* __restrict__ dst, int* __restrict__ deg) {
    int e = blockIdx.x * blockDim.x + threadIdx.x;
    if (e < NE) atomicAdd(&deg[dst[e]], 1);
}

// ---------------- kernel 3: dinv = rsqrt(deg + self-loop) ----------------
__global__ void k_dinv(const int* __restrict__ deg, float* __restrict__ dinv) {
    int i = blockIdx.x * blockDim.x + threadIdx.x;
    if (i < N_NODES) dinv[i] = rsqrtf((float)deg[i] + 1.0f);
}

// ---------------- kernel 4: agg init with self-loop term (agent rows only) ----------------
__global__ void k_agg_init(const float* __restrict__ x, const float* __restrict__ dinv,
                           float* __restrict__ agg) {
    int t = blockIdx.x * blockDim.x + threadIdx.x;
    if (t >= N_AGENT * HID) return;
    int i = t >> 5;
    float d = dinv[i];
    agg[t] = x[t] * d * d;
}

// ---------------- kernel 5: edge aggregation (dominant) ----------------
__global__ void k_aggregate(const int* __restrict__ src, const int* __restrict__ dst,
                            const float* __restrict__ dinv, const float* __restrict__ x,
                            float* __restrict__ agg) {
    int t = blockIdx.x * blockDim.x + threadIdx.x;   // < NE*32 = 102,400,000
    int e = t >> 5;
    if (e >= NE) return;
    int d = dst[e];
    if (d >= N_AGENT) return;                         // discarded downstream
    int c = t & 31;
    int s = src[e];
    float nrm = dinv[s] * dinv[d];
    unsafeAtomicAdd(&agg[(size_t)d * HID + c], x[(size_t)s * HID + c] * nrm);
}

// ---------------- kernel 6: gates + MLP per agent node ----------------
__global__ __launch_bounds__(256) void k_node_out(
        const float* __restrict__ agg,
        const float* __restrict__ Mz, const float* __restrict__ Mh,
        const float* __restrict__ bz_eff, const float* __restrict__ bh_eff,
        const float* __restrict__ s_ptr,
        const float* __restrict__ W1, const float* __restrict__ b1,
        const float* __restrict__ W2, const float* __restrict__ b2,
        float* __restrict__ out) {
    __shared__ float sMz[1024], sMh[1024], sW1[2048], sW2[6400];
    __shared__ float sbz[32], sbh[32], sb1[64], sb2[100];
    for (int t = threadIdx.x; t < 1024; t += 256) { sMz[t] = Mz[t]; sMh[t] = Mh[t]; }
    for (int t = threadIdx.x; t < 2048; t += 256) sW1[t] = W1[t];
    for (int t = threadIdx.x; t < 6400; t += 256) sW2[t] = W2[t];
    if (threadIdx.x < 32) { sbz[threadIdx.x] = bz_eff[threadIdx.x]; sbh[threadIdx.x] = bh_eff[threadIdx.x]; }
    if (threadIdx.x < 64) sb1[threadIdx.x] = b1[threadIdx.x];
    if (threadIdx.x < 100) sb2[threadIdx.x] = b2[threadIdx.x];
    __syncthreads();
    const float s = *s_ptr;
    const int lane = threadIdx.x & 31;
    const int group = threadIdx.x >> 5;               // 8 groups / block
    const int stride = gridDim.x * 8;
    for (int i = blockIdx.x * 8 + group; i < N_AGENT; i += stride) {
        float a = agg[(size_t)i * HID + lane];
        // gates: uz = a . Mz[:,lane], uh = a . Mh[:,lane]
        float uz = sbz[lane], uh = sbh[lane];
#pragma unroll
        for (int k = 0; k < 32; ++k) {
            float ak = __shfl(a, k, 32);
            uz += ak * sMz[k * 32 + lane];
            uh += ak * sMh[k * 32 + lane];
        }
        float z = 1.0f / (1.0f + expf(-uz));
        float h = s * (1.0f - z) * tanhf(uh);
        h = fmaxf(h, 0.0f);
        // MLP1: 32 -> 64, relu
        float t0 = sb1[lane], t1 = sb1[lane + 32];
#pragma unroll
        for (int k = 0; k < 32; ++k) {
            float hk = __shfl(h, k, 32);
            t0 += hk * sW1[k * 64 + lane];
            t1 += hk * sW1[k * 64 + lane + 32];
        }
        t0 = fmaxf(t0, 0.0f); t1 = fmaxf(t1, 0.0f);
        // MLP2: 64 -> 100
        int j3 = (lane < 4) ? (lane + 96) : 99;       // clamp to stay in bounds
        float o0 = sb2[lane];
        float o1 = sb2[lane + 32];
        float o2 = sb2[lane + 64];
        float o3 = sb2[j3];
#pragma unroll
        for (int k = 0; k < 32; ++k) {
            float ta = __shfl(t0, k, 32);
            float tb = __shfl(t1, k, 32);
            o0 += ta * sW2[k * 100 + lane]      + tb * sW2[(k + 32) * 100 + lane];
            o1 += ta * sW2[k * 100 + lane + 32] + tb * sW2[(k + 32) * 100 + lane + 32];
            o2 += ta * sW2[k * 100 + lane + 64] + tb * sW2[(k + 32) * 100 + lane + 64];
            o3 += ta * sW2[k * 100 + j3]        + tb * sW2[(k + 32) * 100 + j3];
        }
        float* orow = out + (size_t)i * 100;
        orow[lane] = o0;
        orow[lane + 32] = o1;
        orow[lane + 64] = o2;
        if (lane < 4) orow[lane + 96] = o3;
    }
}

extern "C" void kernel_launch(void* const* d_in, const int* in_sizes, int n_in,
                              void* d_out, int out_size, void* d_ws, size_t ws_size,
                              hipStream_t stream) {
    const float* agent_x = (const float*)d_in[0];
    const float* map_x   = (const float*)d_in[1];
    const int*   ei      = (const int*)d_in[2];
    const float* W_agent = (const float*)d_in[3];
    const float* b_agent = (const float*)d_in[4];
    const float* W_map   = (const float*)d_in[5];
    const float* b_map   = (const float*)d_in[6];
    const float* Wz_c    = (const float*)d_in[7];
    const float* bz_c    = (const float*)d_in[8];
    // d_in[9], d_in[10]: Wr_c, br_c — dead (r multiplied by zeros_h)
    const float* Wh_c    = (const float*)d_in[11];
    const float* bh_c    = (const float*)d_in[12];
    const float* Wz_l    = (const float*)d_in[13];
    const float* bz_l    = (const float*)d_in[14];
    // d_in[15], d_in[16]: Wr_l, br_l — dead
    const float* Wh_l    = (const float*)d_in[17];
    const float* bh_l    = (const float*)d_in[18];
    const float* attn    = (const float*)d_in[19];
    const float* W1      = (const float*)d_in[20];
    const float* b1      = (const float*)d_in[21];
    const float* W2      = (const float*)d_in[22];
    const float* b2      = (const float*)d_in[23];
    float* out = (float*)d_out;

    const int* e_src = ei;
    const int* e_dst = ei + NE;

    float* ws   = (float*)d_ws;
    float* x    = ws;                    // N_NODES*32 = 3,200,000
    float* agg  = ws + 3200000;          // N_AGENT*32 = 1,920,000
    int*   deg  = (int*)(ws + 5120000);  // N_NODES    =   100,000
    float* dinv = ws + 5220000;          // N_NODES    =   100,000
    float* Mz   = ws + 5320000;          // 1024
    float* Mh   = ws + 5321024;          // 1024
    float* bz   = ws + 5322048;          // 32
    float* bh   = ws + 5322080;          // 32
    float* sS   = ws + 5322112;          // 1

    k_precompute<<<1, 1024, 0, stream>>>(Wz_c, bz_c, Wh_c, bh_c, Wz_l, bz_l,
                                         Wh_l, bh_l, attn, Mz, Mh, bz, bh, sS);
    k_encode<<<(N_NODES * HID + 255) / 256, 256, 0, stream>>>(
        agent_x, map_x, W_agent, b_agent, W_map, b_map, x);
    hipMemsetAsync(deg, 0, (size_t)N_NODES * sizeof(int), stream);
    k_degree<<<(NE + 255) / 256, 256, 0, stream>>>(e_dst, deg);
    k_dinv<<<(N_NODES + 255) / 256, 256, 0, stream>>>(deg, dinv);
    k_agg_init<<<(N_AGENT * HID + 255) / 256, 256, 0, stream>>>(x, dinv, agg);
    k_aggregate<<<(NE * HID + 255) / 256, 256, 0, stream>>>(e_src, e_dst, dinv, x, agg);
    k_node_out<<<1024, 256, 0, stream>>>(agg, Mz, Mh, bz, bh, sS, W1, b1, W2, b2, out);
}

// Round 2
// 622.722 us; speedup vs baseline: 1.1308x; 1.1308x over previous
//
#include <hip/hip_runtime.h>
#include <math.h>

#define N_AGENT 60000
#define N_MAP   40000
#define N_NODES 100000
#define NE      3200000
#define HID     32
#define PERIODS 30

// ---------------- kernel 0: fold weights, softmax sum ----------------
__global__ void k_precompute(const float* Wz_c, const float* bz_c,
                             const float* Wh_c, const float* bh_c,
                             const float* Wz_l, const float* bz_l,
                             const float* Wh_l, const float* bh_l,
                             const float* attn,
                             float* Mz, float* Mh, float* bz_eff, float* bh_eff,
                             float* s_out) {
    int t = threadIdx.x;            // blockDim = 1024
    int k = t >> 5, c = t & 31;
    float mz = 0.f, mh = 0.f;
    for (int j = 0; j < HID; ++j) {
        mz += Wz_c[k * HID + j] * Wz_l[j * HID + c];   // Wz_l rows 0..31 (zeros half dead)
        mh += Wh_c[k * HID + j] * Wh_l[j * HID + c];
    }
    Mz[t] = mz; Mh[t] = mh;
    if (t < HID) {
        float bz = bz_l[t], bh = bh_l[t];
        for (int j = 0; j < HID; ++j) {
            bz += bz_c[j] * Wz_l[j * HID + t];
            bh += bh_c[j] * Wh_l[j * HID + t];
        }
        bz_eff[t] = bz; bh_eff[t] = bh;
    }
    if (t == 0) {
        float m = -1e30f;
        for (int i = 0; i < PERIODS; ++i) m = fmaxf(m, attn[i]);
        float S = 0.f;
        for (int i = 0; i < PERIODS; ++i) S += expf(attn[i] - m);
        float s = 0.f;
        for (int i = 0; i < PERIODS; ++i) s += expf(attn[i] - m) / S;
        *s_out = s;
    }
}

// ---------------- kernel 1: node encoders ----------------
__global__ void k_encode(const float* __restrict__ agent_x, const float* __restrict__ map_x,
                         const float* __restrict__ W_agent, const float* __restrict__ b_agent,
                         const float* __restrict__ W_map, const float* __restrict__ b_map,
                         float* __restrict__ x) {
    int t = blockIdx.x * blockDim.x + threadIdx.x;
    if (t >= N_NODES * HID) return;
    int i = t >> 5, c = t & 31;
    float acc;
    if (i < N_AGENT) {
        const float* row = agent_x + (size_t)i * 9;
        acc = b_agent[c];
#pragma unroll
        for (int k = 0; k < 9; ++k) acc += row[k] * W_agent[k * HID + c];
    } else {
        const float* row = map_x + (size_t)(i - N_AGENT) * 6;
        acc = b_map[c];
#pragma unroll
        for (int k = 0; k < 6; ++k) acc += row[k] * W_map[k * HID + c];
    }
    x[t] = acc;
}

// ---------------- kernel 2: in-degree count (all dsts) ----------------
__global__ void k_degree(const int* __restrict__ dst, int* __restrict__ deg) {
    int e = blockIdx.x * blockDim.x + threadIdx.x;
    if (e < NE) atomicAdd(&deg[dst[e]], 1);
}

// ---------------- kernel 3: dinv = rsqrt(deg + self-loop) ----------------
__global__ void k_dinv(const int* __restrict__ deg, float* __restrict__ dinv) {
    int i = blockIdx.x * blockDim.x + threadIdx.x;
    if (i < N_NODES) dinv[i] = rsqrtf((float)deg[i] + 1.0f);
}

// ---------------- scan kernels: exclusive scan of deg[0..N_AGENT) ----------------
__global__ void k_scan1(const int* __restrict__ deg, int* __restrict__ partial) {
    __shared__ int tmp[256];
    int i = blockIdx.x * 256 + threadIdx.x;
    int v = (i < N_AGENT) ? deg[i] : 0;
    tmp[threadIdx.x] = v;
    __syncthreads();
    for (int s = 128; s > 0; s >>= 1) {
        if (threadIdx.x < s) tmp[threadIdx.x] += tmp[threadIdx.x + s];
        __syncthreads();
    }
    if (threadIdx.x == 0) partial[blockIdx.x] = tmp[0];
}

__global__ void k_scan2(int* __restrict__ partial, int nblocks) {
    // single block of 256; exclusive scan in place
    __shared__ int tmp[256];
    int t = threadIdx.x;
    int v = (t < nblocks) ? partial[t] : 0;
    tmp[t] = v;
    __syncthreads();
    for (int s = 1; s < 256; s <<= 1) {
        int add = (t >= s) ? tmp[t - s] : 0;
        __syncthreads();
        tmp[t] += add;
        __syncthreads();
    }
    if (t < nblocks) partial[t] = tmp[t] - v;   // exclusive
}

__global__ void k_scan3(const int* __restrict__ deg, const int* __restrict__ partial,
                        int* __restrict__ off, int* __restrict__ cursor) {
    __shared__ int tmp[256];
    int t = threadIdx.x;
    int i = blockIdx.x * 256 + t;
    int v = (i < N_AGENT) ? deg[i] : 0;
    tmp[t] = v;
    __syncthreads();
    for (int s = 1; s < 256; s <<= 1) {
        int add = (t >= s) ? tmp[t - s] : 0;
        __syncthreads();
        tmp[t] += add;
        __syncthreads();
    }
    int excl = tmp[t] - v + partial[blockIdx.x];
    if (i < N_AGENT) {
        off[i] = excl;
        cursor[i] = excl;
        if (i == N_AGENT - 1) off[N_AGENT] = excl + v;
    }
}

// ---------------- bucket: scatter edge srcs into per-dst lists ----------------
__global__ void k_bucket(const int* __restrict__ src, const int* __restrict__ dst,
                         int* __restrict__ cursor, int* __restrict__ ebuf) {
    int e = blockIdx.x * blockDim.x + threadIdx.x;
    if (e >= NE) return;
    int d = dst[e];
    if (d >= N_AGENT) return;
    int pos = atomicAdd(&cursor[d], 1);
    ebuf[pos] = src[e];
}

// ---------------- gather: one 32-lane group per dst node ----------------
__global__ __launch_bounds__(256) void k_gather(const int* __restrict__ off,
                          const int* __restrict__ ebuf,
                          const float* __restrict__ dinv, const float* __restrict__ x,
                          float* __restrict__ agg) {
    int c = threadIdx.x & 31;
    int i = blockIdx.x * 8 + (threadIdx.x >> 5);
    if (i >= N_AGENT) return;
    float di = dinv[i];
    float acc = x[(size_t)i * HID + c] * di;        // self-loop (one dinv applied at end)
    int j = off[i], jend = off[i + 1];
    for (; j + 1 < jend; j += 2) {
        int s0 = ebuf[j], s1 = ebuf[j + 1];
        float w0 = dinv[s0], w1 = dinv[s1];
        float x0 = x[(size_t)s0 * HID + c];
        float x1 = x[(size_t)s1 * HID + c];
        acc += x0 * w0 + x1 * w1;
    }
    if (j < jend) {
        int s0 = ebuf[j];
        acc += x[(size_t)s0 * HID + c] * dinv[s0];
    }
    agg[(size_t)i * HID + c] = acc * di;
}

// ---------------- fallback: atomic scatter (old path) ----------------
__global__ void k_agg_init(const float* __restrict__ x, const float* __restrict__ dinv,
                           float* __restrict__ agg) {
    int t = blockIdx.x * blockDim.x + threadIdx.x;
    if (t >= N_AGENT * HID) return;
    int i = t >> 5;
    float d = dinv[i];
    agg[t] = x[t] * d * d;
}

__global__ void k_aggregate(const int* __restrict__ src, const int* __restrict__ dst,
                            const float* __restrict__ dinv, const float* __restrict__ x,
                            float* __restrict__ agg) {
    int t = blockIdx.x * blockDim.x + threadIdx.x;
    int e = t >> 5;
    if (e >= NE) return;
    int d = dst[e];
    if (d >= N_AGENT) return;
    int c = t & 31;
    int s = src[e];
    float nrm = dinv[s] * dinv[d];
    unsafeAtomicAdd(&agg[(size_t)d * HID + c], x[(size_t)s * HID + c] * nrm);
}

// ---------------- gates + MLP per agent node ----------------
__global__ __launch_bounds__(256) void k_node_out(
        const float* __restrict__ agg,
        const float* __restrict__ Mz, const float* __restrict__ Mh,
        const float* __restrict__ bz_eff, const float* __restrict__ bh_eff,
        const float* __restrict__ s_ptr,
        const float* __restrict__ W1, const float* __restrict__ b1,
        const float* __restrict__ W2, const float* __restrict__ b2,
        float* __restrict__ out) {
    __shared__ float sMz[1024], sMh[1024], sW1[2048], sW2[6400];
    __shared__ float sbz[32], sbh[32], sb1[64], sb2[100];
    for (int t = threadIdx.x; t < 1024; t += 256) { sMz[t] = Mz[t]; sMh[t] = Mh[t]; }
    for (int t = threadIdx.x; t < 2048; t += 256) sW1[t] = W1[t];
    for (int t = threadIdx.x; t < 6400; t += 256) sW2[t] = W2[t];
    if (threadIdx.x < 32) { sbz[threadIdx.x] = bz_eff[threadIdx.x]; sbh[threadIdx.x] = bh_eff[threadIdx.x]; }
    if (threadIdx.x < 64) sb1[threadIdx.x] = b1[threadIdx.x];
    if (threadIdx.x < 100) sb2[threadIdx.x] = b2[threadIdx.x];
    __syncthreads();
    const float s = *s_ptr;
    const int lane = threadIdx.x & 31;
    const int group = threadIdx.x >> 5;               // 8 groups / block
    const int stride = gridDim.x * 8;
    for (int i = blockIdx.x * 8 + group; i < N_AGENT; i += stride) {
        float a = agg[(size_t)i * HID + lane];
        float uz = sbz[lane], uh = sbh[lane];
#pragma unroll
        for (int k = 0; k < 32; ++k) {
            float ak = __shfl(a, k, 32);
            uz += ak * sMz[k * 32 + lane];
            uh += ak * sMh[k * 32 + lane];
        }
        float z = 1.0f / (1.0f + expf(-uz));
        float h = s * (1.0f - z) * tanhf(uh);
        h = fmaxf(h, 0.0f);
        float t0 = sb1[lane], t1 = sb1[lane + 32];
#pragma unroll
        for (int k = 0; k < 32; ++k) {
            float hk = __shfl(h, k, 32);
            t0 += hk * sW1[k * 64 + lane];
            t1 += hk * sW1[k * 64 + lane + 32];
        }
        t0 = fmaxf(t0, 0.0f); t1 = fmaxf(t1, 0.0f);
        int j3 = (lane < 4) ? (lane + 96) : 99;
        float o0 = sb2[lane];
        float o1 = sb2[lane + 32];
        float o2 = sb2[lane + 64];
        float o3 = sb2[j3];
#pragma unroll
        for (int k = 0; k < 32; ++k) {
            float ta = __shfl(t0, k, 32);
            float tb = __shfl(t1, k, 32);
            o0 += ta * sW2[k * 100 + lane]      + tb * sW2[(k + 32) * 100 + lane];
            o1 += ta * sW2[k * 100 + lane + 32] + tb * sW2[(k + 32) * 100 + lane + 32];
            o2 += ta * sW2[k * 100 + lane + 64] + tb * sW2[(k + 32) * 100 + lane + 64];
            o3 += ta * sW2[k * 100 + j3]        + tb * sW2[(k + 32) * 100 + j3];
        }
        float* orow = out + (size_t)i * 100;
        orow[lane] = o0;
        orow[lane + 32] = o1;
        orow[lane + 64] = o2;
        if (lane < 4) orow[lane + 96] = o3;
    }
}

extern "C" void kernel_launch(void* const* d_in, const int* in_sizes, int n_in,
                              void* d_out, int out_size, void* d_ws, size_t ws_size,
                              hipStream_t stream) {
    const float* agent_x = (const float*)d_in[0];
    const float* map_x   = (const float*)d_in[1];
    const int*   ei      = (const int*)d_in[2];
    const float* W_agent = (const float*)d_in[3];
    const float* b_agent = (const float*)d_in[4];
    const float* W_map   = (const float*)d_in[5];
    const float* b_map   = (const float*)d_in[6];
    const float* Wz_c    = (const float*)d_in[7];
    const float* bz_c    = (const float*)d_in[8];
    const float* Wh_c    = (const float*)d_in[11];
    const float* bh_c    = (const float*)d_in[12];
    const float* Wz_l    = (const float*)d_in[13];
    const float* bz_l    = (const float*)d_in[14];
    const float* Wh_l    = (const float*)d_in[17];
    const float* bh_l    = (const float*)d_in[18];
    const float* attn    = (const float*)d_in[19];
    const float* W1      = (const float*)d_in[20];
    const float* b1      = (const float*)d_in[21];
    const float* W2      = (const float*)d_in[22];
    const float* b2      = (const float*)d_in[23];
    float* out = (float*)d_out;

    const int* e_src = ei;
    const int* e_dst = ei + NE;

    // workspace layout (float-element offsets)
    float* ws     = (float*)d_ws;
    float* x      = ws;                        // 3,200,000
    float* agg    = ws + 3200000;              // 1,920,000
    int*   deg    = (int*)(ws + 5120000);      //   100,000
    float* dinv   = ws + 5220000;              //   100,000
    float* Mz     = ws + 5320000;              // 1024
    float* Mh     = ws + 5321024;              // 1024
    float* bz     = ws + 5322048;              // 32
    float* bh     = ws + 5322080;              // 32
    float* sS     = ws + 5322112;              // 1 (pad to 5322240)
    int*   off    = (int*)(ws + 5322240);      // 60,001 (pad 60,416)
    int*   cursor = (int*)(ws + 5382656);      // 60,000 (pad 60,416)
    int*   partial= (int*)(ws + 5443072);      // 256
    int*   ebuf   = (int*)(ws + 5443328);      // 3,200,000 -> end 8,643,328
    const size_t NEED = (size_t)8643328 * 4;

    const int SCAN_BLOCKS = (N_AGENT + 255) / 256;   // 235

    k_precompute<<<1, 1024, 0, stream>>>(Wz_c, bz_c, Wh_c, bh_c, Wz_l, bz_l,
                                         Wh_l, bh_l, attn, Mz, Mh, bz, bh, sS);
    k_encode<<<(N_NODES * HID + 255) / 256, 256, 0, stream>>>(
        agent_x, map_x, W_agent, b_agent, W_map, b_map, x);
    hipMemsetAsync(deg, 0, (size_t)N_NODES * sizeof(int), stream);
    k_degree<<<(NE + 255) / 256, 256, 0, stream>>>(e_dst, deg);
    k_dinv<<<(N_NODES + 255) / 256, 256, 0, stream>>>(deg, dinv);

    if (ws_size >= NEED) {
        // CSR gather path
        k_scan1<<<SCAN_BLOCKS, 256, 0, stream>>>(deg, partial);
        k_scan2<<<1, 256, 0, stream>>>(partial, SCAN_BLOCKS);
        k_scan3<<<SCAN_BLOCKS, 256, 0, stream>>>(deg, partial, off, cursor);
        k_bucket<<<(NE + 255) / 256, 256, 0, stream>>>(e_src, e_dst, cursor, ebuf);
        k_gather<<<(N_AGENT + 7) / 8, 256, 0, stream>>>(off, ebuf, dinv, x, agg);
    } else {
        // fallback: atomic scatter
        k_agg_init<<<(N_AGENT * HID + 255) / 256, 256, 0, stream>>>(x, dinv, agg);
        k_aggregate<<<((size_t)NE * HID + 255) / 256, 256, 0, stream>>>(e_src, e_dst, dinv, x, agg);
    }

    k_node_out<<<1024, 256, 0, stream>>>(agg, Mz, Mh, bz, bh, sS, W1, b1, W2, b2, out);
}

// Round 3
// 613.564 us; speedup vs baseline: 1.1477x; 1.0149x over previous
//
#include <hip/hip_runtime.h>
#include <math.h>

#define N_AGENT 60000
#define N_MAP   40000
#define N_NODES 100000
#define NE      3200000
#define HID     32
#define PERIODS 30

#define NBUCK   391        // ceil(100000/256) buckets of 256 dst nodes
#define CAP     12288      // per-bucket capacity (mean 8184, huge margin)
#define TILE    4096       // edges per partition block
#define PTHREADS 512

// ---------------- kernel 0: fold weights, softmax sum, cursor init ----------------
__global__ void k_precompute(const float* Wz_c, const float* bz_c,
                             const float* Wh_c, const float* bh_c,
                             const float* Wz_l, const float* bz_l,
                             const float* Wh_l, const float* bh_l,
                             const float* attn,
                             float* Mz, float* Mh, float* bz_eff, float* bh_eff,
                             float* s_out, int* cursor) {
    int t = threadIdx.x;            // blockDim = 1024
    int k = t >> 5, c = t & 31;
    float mz = 0.f, mh = 0.f;
    for (int j = 0; j < HID; ++j) {
        mz += Wz_c[k * HID + j] * Wz_l[j * HID + c];   // Wz_l rows 0..31 (zeros half dead)
        mh += Wh_c[k * HID + j] * Wh_l[j * HID + c];
    }
    Mz[t] = mz; Mh[t] = mh;
    if (t < NBUCK) cursor[t] = t * CAP;
    if (t < HID) {
        float bz = bz_l[t], bh = bh_l[t];
        for (int j = 0; j < HID; ++j) {
            bz += bz_c[j] * Wz_l[j * HID + t];
            bh += bh_c[j] * Wh_l[j * HID + t];
        }
        bz_eff[t] = bz; bh_eff[t] = bh;
    }
    if (t == 0) {
        float m = -1e30f;
        for (int i = 0; i < PERIODS; ++i) m = fmaxf(m, attn[i]);
        float S = 0.f;
        for (int i = 0; i < PERIODS; ++i) S += expf(attn[i] - m);
        float s = 0.f;
        for (int i = 0; i < PERIODS; ++i) s += expf(attn[i] - m) / S;
        *s_out = s;
    }
}

// ---------------- kernel 1: node encoders ----------------
__global__ void k_encode(const float* __restrict__ agent_x, const float* __restrict__ map_x,
                         const float* __restrict__ W_agent, const float* __restrict__ b_agent,
                         const float* __restrict__ W_map, const float* __restrict__ b_map,
                         float* __restrict__ x) {
    int t = blockIdx.x * blockDim.x + threadIdx.x;
    if (t >= N_NODES * HID) return;
    int i = t >> 5, c = t & 31;
    float acc;
    if (i < N_AGENT) {
        const float* row = agent_x + (size_t)i * 9;
        acc = b_agent[c];
#pragma unroll
        for (int k = 0; k < 9; ++k) acc += row[k] * W_agent[k * HID + c];
    } else {
        const float* row = map_x + (size_t)(i - N_AGENT) * 6;
        acc = b_map[c];
#pragma unroll
        for (int k = 0; k < 6; ++k) acc += row[k] * W_map[k * HID + c];
    }
    x[t] = acc;
}

// ---------------- kernel 2: LDS-staged partition (multisplit) ----------------
// pack = src | (dst_low << 17); bucket = dst >> 8
__global__ __launch_bounds__(PTHREADS) void k_partition(
        const int* __restrict__ src, const int* __restrict__ dst,
        int* __restrict__ cursor, int* __restrict__ ebuf) {
    __shared__ int sCnt[NBUCK + 1];
    __shared__ int sBase[NBUCK + 1];
    __shared__ int sGbase[NBUCK];
    __shared__ int sScan[PTHREADS];
    __shared__ int sReorder[TILE];
    int t = threadIdx.x;
    int tileBase = blockIdx.x * TILE;
    int tcount = NE - tileBase; if (tcount > TILE) tcount = TILE;

    if (t < NBUCK) sCnt[t] = 0;
    __syncthreads();

    int pb[8]; int pp[8];
#pragma unroll
    for (int k = 0; k < 8; ++k) {
        int e = tileBase + t + k * PTHREADS;
        pb[k] = -1;
        if (e < NE) {
            int s = src[e], d = dst[e];
            pb[k] = d >> 8;
            pp[k] = s | ((d & 255) << 17);
            atomicAdd(&sCnt[pb[k]], 1);
        }
    }
    __syncthreads();

    // inclusive scan of sCnt via sScan (Hillis-Steele over 512 threads)
    int v = (t < NBUCK) ? sCnt[t] : 0;
    sScan[t] = v;
    __syncthreads();
    for (int s = 1; s < PTHREADS; s <<= 1) {
        int a = (t >= s) ? sScan[t - s] : 0;
        __syncthreads();
        sScan[t] += a;
        __syncthreads();
    }
    if (t <= NBUCK) sBase[t] = sScan[t] - v;   // exclusive; sBase[NBUCK] = tile total
    __syncthreads();
    // reserve global space, reset counters for rank pass
    if (t < NBUCK) {
        if (sCnt[t] > 0) sGbase[t] = atomicAdd(&cursor[t], sCnt[t]);
        sCnt[t] = 0;
    }
    __syncthreads();
    // rank + reorder in LDS
#pragma unroll
    for (int k = 0; k < 8; ++k) {
        if (pb[k] >= 0) {
            int r = atomicAdd(&sCnt[pb[k]], 1);
            sReorder[sBase[pb[k]] + r] = pp[k];
        }
    }
    __syncthreads();
    // coalesced flush: binary-search bucket owning slot j
#pragma unroll
    for (int k = 0; k < 8; ++k) {
        int j = t + k * PTHREADS;
        if (j < tcount) {
            int lo = 0, hi = NBUCK;
            while (hi - lo > 1) {
                int m = (lo + hi) >> 1;
                if (sBase[m] <= j) lo = m; else hi = m;
            }
            ebuf[sGbase[lo] + (j - sBase[lo])] = sReorder[j];
        }
    }
}

// ---------------- kernel 3: per-bucket degree histogram -> dinv ----------------
__global__ __launch_bounds__(256) void k_hist(const int* __restrict__ cursor,
                                              const int* __restrict__ ebuf,
                                              float* __restrict__ dinv) {
    __shared__ int h[256];
    int t = threadIdx.x;
    int b = blockIdx.x;
    h[t] = 0;
    __syncthreads();
    int start = b * CAP;
    int cnt = cursor[b] - start;
    for (int j = t; j < cnt; j += 256)
        atomicAdd(&h[(ebuf[start + j] >> 17) & 255], 1);
    __syncthreads();
    int node = b * 256 + t;
    if (node < N_NODES) dinv[node] = rsqrtf((float)h[t] + 1.0f);
}

// ---------------- kernel 4: fused aggregate + gates + MLP ----------------
__global__ __launch_bounds__(1024) void k_agg_fused(
        const int* __restrict__ cursor, const int* __restrict__ ebuf,
        const float* __restrict__ dinv, const float* __restrict__ x,
        const float* __restrict__ Mz, const float* __restrict__ Mh,
        const float* __restrict__ bz_eff, const float* __restrict__ bh_eff,
        const float* __restrict__ s_ptr,
        const float* __restrict__ W1, const float* __restrict__ b1,
        const float* __restrict__ W2, const float* __restrict__ b2,
        float* __restrict__ out) {
    __shared__ float acc[256 * 32];     // 32 KB accumulator (256 dst rows)
    __shared__ float sMz[1024], sMh[1024], sW1[2048], sW2[6400];
    __shared__ float sbz[32], sbh[32], sb1[64], sb2[100];
    int t = threadIdx.x;
    for (int j = t; j < 256 * 32; j += 1024) acc[j] = 0.0f;
    sMz[t] = Mz[t]; sMh[t] = Mh[t];
    for (int j = t; j < 2048; j += 1024) sW1[j] = W1[j];
    for (int j = t; j < 6400; j += 1024) sW2[j] = W2[j];
    if (t < 32) { sbz[t] = bz_eff[t]; sbh[t] = bh_eff[t]; }
    if (t >= 32 && t < 96) sb1[t - 32] = b1[t - 32];
    if (t >= 128 && t < 228) sb2[t - 128] = b2[t - 128];
    __syncthreads();

    const int b = blockIdx.x;
    const int c = t & 31;
    const int g = t >> 5;               // 32 groups of 32 lanes
    const int start = b * CAP;
    const int cnt = cursor[b] - start;
    const int nodeBase = b * 256;

    // edge loop, unrolled x2 for outstanding gathers
    int j = g;
    for (; j + 32 < cnt; j += 64) {
        int p0 = ebuf[start + j];
        int p1 = ebuf[start + j + 32];
        int s0 = p0 & 0x1FFFF, dl0 = (p0 >> 17) & 255;
        int s1 = p1 & 0x1FFFF, dl1 = (p1 >> 17) & 255;
        float w0 = dinv[s0], w1 = dinv[s1];
        float x0 = x[(size_t)s0 * HID + c];
        float x1 = x[(size_t)s1 * HID + c];
        if (nodeBase + dl0 < N_AGENT) atomicAdd(&acc[dl0 * 32 + c], x0 * w0);
        if (nodeBase + dl1 < N_AGENT) atomicAdd(&acc[dl1 * 32 + c], x1 * w1);
    }
    if (j < cnt) {
        int p0 = ebuf[start + j];
        int s0 = p0 & 0x1FFFF, dl0 = (p0 >> 17) & 255;
        if (nodeBase + dl0 < N_AGENT)
            atomicAdd(&acc[dl0 * 32 + c], x[(size_t)s0 * HID + c] * dinv[s0]);
    }
    __syncthreads();

    const float s = *s_ptr;
    // epilogue: up to 8 rows per group
    for (int r = g; r < 256; r += 32) {
        int i = nodeBase + r;
        if (i >= N_AGENT) break;
        float di = dinv[i];
        float a = (acc[r * 32 + c] + x[(size_t)i * HID + c] * di) * di;
        float uz = sbz[c], uh = sbh[c];
#pragma unroll
        for (int k = 0; k < 32; ++k) {
            float ak = __shfl(a, k, 32);
            uz += ak * sMz[k * 32 + c];
            uh += ak * sMh[k * 32 + c];
        }
        float z = 1.0f / (1.0f + expf(-uz));
        float h = s * (1.0f - z) * tanhf(uh);
        h = fmaxf(h, 0.0f);
        float t0 = sb1[c], t1 = sb1[c + 32];
#pragma unroll
        for (int k = 0; k < 32; ++k) {
            float hk = __shfl(h, k, 32);
            t0 += hk * sW1[k * 64 + c];
            t1 += hk * sW1[k * 64 + c + 32];
        }
        t0 = fmaxf(t0, 0.0f); t1 = fmaxf(t1, 0.0f);
        int j3 = (c < 4) ? (c + 96) : 99;
        float o0 = sb2[c];
        float o1 = sb2[c + 32];
        float o2 = sb2[c + 64];
        float o3 = sb2[j3];
#pragma unroll
        for (int k = 0; k < 32; ++k) {
            float ta = __shfl(t0, k, 32);
            float tb = __shfl(t1, k, 32);
            o0 += ta * sW2[k * 100 + c]      + tb * sW2[(k + 32) * 100 + c];
            o1 += ta * sW2[k * 100 + c + 32] + tb * sW2[(k + 32) * 100 + c + 32];
            o2 += ta * sW2[k * 100 + c + 64] + tb * sW2[(k + 32) * 100 + c + 64];
            o3 += ta * sW2[k * 100 + j3]     + tb * sW2[(k + 32) * 100 + j3];
        }
        float* orow = out + (size_t)i * 100;
        orow[c] = o0;
        orow[c + 32] = o1;
        orow[c + 64] = o2;
        if (c < 4) orow[c + 96] = o3;
    }
}

extern "C" void kernel_launch(void* const* d_in, const int* in_sizes, int n_in,
                              void* d_out, int out_size, void* d_ws, size_t ws_size,
                              hipStream_t stream) {
    const float* agent_x = (const float*)d_in[0];
    const float* map_x   = (const float*)d_in[1];
    const int*   ei      = (const int*)d_in[2];
    const float* W_agent = (const float*)d_in[3];
    const float* b_agent = (const float*)d_in[4];
    const float* W_map   = (const float*)d_in[5];
    const float* b_map   = (const float*)d_in[6];
    const float* Wz_c    = (const float*)d_in[7];
    const float* bz_c    = (const float*)d_in[8];
    const float* Wh_c    = (const float*)d_in[11];
    const float* bh_c    = (const float*)d_in[12];
    const float* Wz_l    = (const float*)d_in[13];
    const float* bz_l    = (const float*)d_in[14];
    const float* Wh_l    = (const float*)d_in[17];
    const float* bh_l    = (const float*)d_in[18];
    const float* attn    = (const float*)d_in[19];
    const float* W1      = (const float*)d_in[20];
    const float* b1      = (const float*)d_in[21];
    const float* W2      = (const float*)d_in[22];
    const float* b2      = (const float*)d_in[23];
    float* out = (float*)d_out;

    const int* e_src = ei;
    const int* e_dst = ei + NE;

    // workspace layout (float-element offsets); total ~32.4 MB
    float* ws     = (float*)d_ws;
    float* x      = ws;                         // 3,200,000
    float* Mz     = ws + 3200000;               // 1024
    float* Mh     = ws + 3201024;               // 1024
    float* bz     = ws + 3202048;               // 32
    float* bh     = ws + 3202080;               // 32
    float* sS     = ws + 3202112;               // 1 (pad to 3202304)
    float* dinv   = ws + 3202304;               // 100,000 (pad to 3302400)
    int*   cursor = (int*)(ws + 3302400);       // 391 (pad 512)
    int*   ebuf   = (int*)(ws + 3302912);       // NBUCK*CAP = 4,804,608 -> end 8,107,520

    k_precompute<<<1, 1024, 0, stream>>>(Wz_c, bz_c, Wh_c, bh_c, Wz_l, bz_l,
                                         Wh_l, bh_l, attn, Mz, Mh, bz, bh, sS, cursor);
    k_encode<<<(N_NODES * HID + 255) / 256, 256, 0, stream>>>(
        agent_x, map_x, W_agent, b_agent, W_map, b_map, x);
    k_partition<<<(NE + TILE - 1) / TILE, PTHREADS, 0, stream>>>(e_src, e_dst, cursor, ebuf);
    k_hist<<<NBUCK, 256, 0, stream>>>(cursor, ebuf, dinv);
    k_agg_fused<<<(N_AGENT + 255) / 256, 1024, 0, stream>>>(
        cursor, ebuf, dinv, x, Mz, Mh, bz, bh, sS, W1, b1, W2, b2, out);
}